// Round 1
// baseline (39.150 us; speedup 1.0000x reference)
//
#include <hip/hip_runtime.h>
#include <hip/hip_bf16.h>

#define HID 16
#define DIN 64
#define NK  32
#define NB  8192

// One block = one k, 512 batch rows (2 per thread).
// Weights are lane-uniform -> backend should emit s_load (scalar cache),
// leaving VALU free for the fma/max/fma chain.
__global__ __launch_bounds__(256, 2) void kan_kernel(
    const float* __restrict__ x,
    const float* __restrict__ iw1, const float* __restrict__ ib1,
    const float* __restrict__ iw2, const float* __restrict__ ib2,
    const float* __restrict__ ow1, const float* __restrict__ ob1,
    const float* __restrict__ ow2, const float* __restrict__ ob2,
    float* __restrict__ out)
{
    const int k      = blockIdx.x & (NK - 1);
    const int bchunk = blockIdx.x >> 5;          // 16 chunks of 512 rows
    const int t      = threadIdx.x;
    const int b0     = bchunk * 512 + t;
    const int b1     = b0 + 256;

    const float* __restrict__ w1k = iw1 + k * DIN * HID;
    const float* __restrict__ c1k = ib1 + k * DIN * HID;
    const float* __restrict__ w2k = iw2 + k * DIN * HID;
    const float* __restrict__ c2k = ib2 + k * DIN;

    const float* __restrict__ xr0 = x + b0 * DIN;
    const float* __restrict__ xr1 = x + b1 * DIN;

    float acc0 = 0.0f, acc1 = 0.0f;

    #pragma unroll 2
    for (int d = 0; d < DIN; ++d) {
        const float x0 = xr0[d];
        const float x1 = xr1[d];
        #pragma unroll
        for (int h = 0; h < HID; ++h) {
            const float w1 = w1k[d * HID + h];
            const float bb = c1k[d * HID + h];
            const float w2 = w2k[d * HID + h];
            float t0 = fmaf(x0, w1, bb);
            float t1 = fmaf(x1, w1, bb);
            t0 = fmaxf(t0, 0.0f);
            t1 = fmaxf(t1, 0.0f);
            acc0 = fmaf(t0, w2, acc0);
            acc1 = fmaf(t1, w2, acc1);
        }
        const float bd = c2k[d];
        acc0 += bd;
        acc1 += bd;
    }

    // Outer net: scalar -> HID -> scalar (per k)
    float o0 = ob2[k];
    float o1 = ob2[k];
    #pragma unroll
    for (int h = 0; h < HID; ++h) {
        const float w  = ow1[k * HID + h];
        const float bo = ob1[k * HID + h];
        const float wo = ow2[k * HID + h];
        float g0 = fmaxf(fmaf(acc0, w, bo), 0.0f);
        float g1 = fmaxf(fmaf(acc1, w, bo), 0.0f);
        o0 = fmaf(g0, wo, o0);
        o1 = fmaf(g1, wo, o1);
    }

    out[b0 * NK + k] = o0;
    out[b1 * NK + k] = o1;
}

extern "C" void kernel_launch(void* const* d_in, const int* in_sizes, int n_in,
                              void* d_out, int out_size, void* d_ws, size_t ws_size,
                              hipStream_t stream) {
    const float* x   = (const float*)d_in[0];
    const float* iw1 = (const float*)d_in[1];
    const float* ib1 = (const float*)d_in[2];
    const float* iw2 = (const float*)d_in[3];
    const float* ib2 = (const float*)d_in[4];
    const float* ow1 = (const float*)d_in[5];
    const float* ob1 = (const float*)d_in[6];
    const float* ow2 = (const float*)d_in[7];
    const float* ob2 = (const float*)d_in[8];
    float* out = (float*)d_out;

    const int grid = (NB / 512) * NK;  // 16 * 32 = 512 blocks
    kan_kernel<<<grid, 256, 0, stream>>>(x, iw1, ib1, iw2, ib2,
                                         ow1, ob1, ow2, ob2, out);
}

// Round 2
// 31.015 us; speedup vs baseline: 1.2623x; 1.2623x over previous
//
#include <hip/hip_runtime.h>
#include <hip/hip_bf16.h>

#define HID 16
#define DIN 64
#define NK  32
#define NB  8192

typedef float v2f __attribute__((ext_vector_type(2)));
typedef float v4f __attribute__((ext_vector_type(4)));

// 1 thread = 1 (b,k) output. Grid 1024 blocks x 256 -> 4 blocks/CU, 16 waves/CU.
// Weights indexed block-uniformly -> s_load (scalar pipe); h-loop packed as
// float2 so backend can emit v_pk_fma_f32 / v_pk_max_f32 (2x fp32 rate).
__global__ __launch_bounds__(256, 4) void kan_kernel(
    const float* __restrict__ x,
    const float* __restrict__ iw1, const float* __restrict__ ib1,
    const float* __restrict__ iw2, const float* __restrict__ ib2,
    const float* __restrict__ ow1, const float* __restrict__ ob1,
    const float* __restrict__ ow2, const float* __restrict__ ob2,
    float* __restrict__ out)
{
    const int k = blockIdx.x & (NK - 1);
    const int b = (blockIdx.x >> 5) * 256 + threadIdx.x;

    const v2f* __restrict__ w1p = (const v2f*)(iw1 + k * DIN * HID);
    const v2f* __restrict__ b1p = (const v2f*)(ib1 + k * DIN * HID);
    const v2f* __restrict__ w2p = (const v2f*)(iw2 + k * DIN * HID);
    const float* __restrict__ c2k = ib2 + k * DIN;

    const float* __restrict__ xr = x + b * DIN;

    v2f acc[4];
    acc[0] = acc[1] = acc[2] = acc[3] = (v2f){0.f, 0.f};
    float bsum = 0.f;   // lane-uniform -> scalar pipe

    for (int d0 = 0; d0 < DIN; d0 += 4) {
        const v4f xv = *(const v4f*)(xr + d0);
        #pragma unroll
        for (int dd = 0; dd < 4; ++dd) {
            const int d = d0 + dd;
            const float xd = xv[dd];
            const v2f xx = {xd, xd};
            #pragma unroll
            for (int hp = 0; hp < 8; ++hp) {
                const v2f w1 = w1p[d * 8 + hp];
                const v2f bb = b1p[d * 8 + hp];
                const v2f w2 = w2p[d * 8 + hp];
                v2f t = __builtin_elementwise_fma(xx, w1, bb);
                t = __builtin_elementwise_max(t, (v2f){0.f, 0.f});
                acc[hp & 3] = __builtin_elementwise_fma(t, w2, acc[hp & 3]);
            }
            bsum += c2k[d];
        }
    }

    const float sk = acc[0].x + acc[0].y + acc[1].x + acc[1].y
                   + acc[2].x + acc[2].y + acc[3].x + acc[3].y + bsum;

    // Outer net: scalar -> HID -> scalar (per k); negligible cost.
    float o = ob2[k];
    #pragma unroll
    for (int h = 0; h < HID; ++h) {
        const float g = fmaxf(fmaf(sk, ow1[k * HID + h], ob1[k * HID + h]), 0.f);
        o = fmaf(g, ow2[k * HID + h], o);
    }

    out[b * NK + k] = o;
}

extern "C" void kernel_launch(void* const* d_in, const int* in_sizes, int n_in,
                              void* d_out, int out_size, void* d_ws, size_t ws_size,
                              hipStream_t stream) {
    const float* x   = (const float*)d_in[0];
    const float* iw1 = (const float*)d_in[1];
    const float* ib1 = (const float*)d_in[2];
    const float* iw2 = (const float*)d_in[3];
    const float* ib2 = (const float*)d_in[4];
    const float* ow1 = (const float*)d_in[5];
    const float* ob1 = (const float*)d_in[6];
    const float* ow2 = (const float*)d_in[7];
    const float* ob2 = (const float*)d_in[8];
    float* out = (float*)d_out;

    const int grid = (NB / 256) * NK;  // 32 * 32 = 1024 blocks
    kan_kernel<<<grid, 256, 0, stream>>>(x, iw1, ib1, iw2, ib2,
                                         ow1, ob1, ow2, ob2, out);
}

// Round 3
// 30.129 us; speedup vs baseline: 1.2994x; 1.0294x over previous
//
#include <hip/hip_runtime.h>
#include <hip/hip_bf16.h>

#define HID 16
#define DIN 64
#define NK  32
#define NB  8192

typedef float v2f __attribute__((ext_vector_type(2)));
typedef float v4f __attribute__((ext_vector_type(4)));

// Block = 128 batch rows x 2 d-halves (256 threads). Grid = 2048 blocks
// -> 8 blocks/CU -> 32 waves/CU (full occupancy) to hide s_load latency.
// Weight addresses forced wave-uniform via readfirstlane -> s_load path.
__global__ __launch_bounds__(256, 8) void kan_kernel(
    const float* __restrict__ x,
    const float* __restrict__ iw1, const float* __restrict__ ib1,
    const float* __restrict__ iw2, const float* __restrict__ ib2,
    const float* __restrict__ ow1, const float* __restrict__ ob1,
    const float* __restrict__ ow2, const float* __restrict__ ob2,
    float* __restrict__ out)
{
    __shared__ float part[256];

    const int k     = blockIdx.x & (NK - 1);
    const int chunk = blockIdx.x >> 5;            // 64 chunks of 128 rows
    const int t     = threadIdx.x;
    const int bl    = t & 127;
    // dh is wave-uniform (waves 0,1 -> 0; waves 2,3 -> 1); force the compiler
    // to see it as uniform so weight loads scalarize to s_load.
    const int dh    = __builtin_amdgcn_readfirstlane(t >> 7);
    const int b     = chunk * 128 + bl;
    const int dbase = dh * 32;

    const v2f* __restrict__ w1p = (const v2f*)(iw1 + (k * DIN + dbase) * HID);
    const v2f* __restrict__ b1p = (const v2f*)(ib1 + (k * DIN + dbase) * HID);
    const v2f* __restrict__ w2p = (const v2f*)(iw2 + (k * DIN + dbase) * HID);
    const float* __restrict__ c2k = ib2 + k * DIN + dbase;

    const float* __restrict__ xr = x + b * DIN + dbase;

    v2f acc[4];
    acc[0] = acc[1] = acc[2] = acc[3] = (v2f){0.f, 0.f};
    float bsum = 0.f;

    for (int d0 = 0; d0 < 32; d0 += 4) {
        const v4f xv = *(const v4f*)(xr + d0);
        #pragma unroll
        for (int dd = 0; dd < 4; ++dd) {
            const int d = d0 + dd;
            const float xd = xv[dd];
            const v2f xx = {xd, xd};
            #pragma unroll
            for (int hp = 0; hp < 8; ++hp) {
                const v2f w1 = w1p[d * 8 + hp];
                const v2f bb = b1p[d * 8 + hp];
                const v2f w2 = w2p[d * 8 + hp];
                v2f tv = __builtin_elementwise_fma(xx, w1, bb);
                tv = __builtin_elementwise_max(tv, (v2f){0.f, 0.f});
                acc[hp & 3] = __builtin_elementwise_fma(tv, w2, acc[hp & 3]);
            }
            bsum += c2k[d];
        }
    }

    part[t] = acc[0].x + acc[0].y + acc[1].x + acc[1].y
            + acc[2].x + acc[2].y + acc[3].x + acc[3].y + bsum;
    __syncthreads();

    if (t < 128) {
        const float sk = part[t] + part[t + 128];
        // Outer net: scalar -> HID -> scalar (per k)
        float o = ob2[k];
        #pragma unroll
        for (int h = 0; h < HID; ++h) {
            const float g = fmaxf(fmaf(sk, ow1[k * HID + h], ob1[k * HID + h]), 0.f);
            o = fmaf(g, ow2[k * HID + h], o);
        }
        out[b * NK + k] = o;
    }
}

extern "C" void kernel_launch(void* const* d_in, const int* in_sizes, int n_in,
                              void* d_out, int out_size, void* d_ws, size_t ws_size,
                              hipStream_t stream) {
    const float* x   = (const float*)d_in[0];
    const float* iw1 = (const float*)d_in[1];
    const float* ib1 = (const float*)d_in[2];
    const float* iw2 = (const float*)d_in[3];
    const float* ib2 = (const float*)d_in[4];
    const float* ow1 = (const float*)d_in[5];
    const float* ob1 = (const float*)d_in[6];
    const float* ow2 = (const float*)d_in[7];
    const float* ob2 = (const float*)d_in[8];
    float* out = (float*)d_out;

    const int grid = (NB / 128) * NK;  // 64 * 32 = 2048 blocks
    kan_kernel<<<grid, 256, 0, stream>>>(x, iw1, ib1, iw2, ib2,
                                         ow1, ob1, ow2, ob2, out);
}